// Round 3
// baseline (995.049 us; speedup 1.0000x reference)
//
#include <hip/hip_runtime.h>
#include <hip/hip_bf16.h>
#include <math.h>

#define NTOK 8192     // B*T
#define DD   1024
#define HH   4096
#define NE   8
#define BM 256
#define BN 256
#define BK 64
#define SLOT_CAP (2 * NTOK + NE * BM)   // 18432

typedef __bf16 bf16;
typedef __bf16 bf16x8 __attribute__((ext_vector_type(8)));
typedef __bf16 bf16x4 __attribute__((ext_vector_type(4)));
typedef float  f32x4  __attribute__((ext_vector_type(4)));

typedef __attribute__((address_space(3))) unsigned char lds_u8;
typedef const __attribute__((address_space(1))) unsigned char g_u8;

__device__ __forceinline__ void gload16(const bf16* g, bf16* l) {
  __builtin_amdgcn_global_load_lds((g_u8*)g, (lds_u8*)l, 16, 0, 0);
}

__device__ __forceinline__ float softplus_f(float v) {
  return fmaxf(v, 0.f) + log1pf(expf(-fabsf(v)));
}

// ---------------- K1: gating (1 wave per token) ----------------
__global__ __launch_bounds__(64) void moe_gate_kernel(
    const float* __restrict__ x, const float* __restrict__ noise,
    const float* __restrict__ gate_w, const float* __restrict__ gate_b,
    const float* __restrict__ var_w,  const float* __restrict__ var_b,
    float* __restrict__ coef2, int* __restrict__ t2e, int* __restrict__ counts)
{
  const int t = blockIdx.x;
  const int lane = threadIdx.x;
  const float* xt = x + (size_t)t * DD;
  float pg[NE], pv[NE];
  #pragma unroll
  for (int e = 0; e < NE; ++e) { pg[e] = 0.f; pv[e] = 0.f; }
  #pragma unroll 4
  for (int i = 0; i < DD / 64; ++i) {
    const int d = lane + i * 64;
    const float xv = xt[d];
    #pragma unroll
    for (int e = 0; e < NE; ++e) {
      pg[e] = fmaf(xv, gate_w[e * DD + d], pg[e]);
      pv[e] = fmaf(xv, var_w[e * DD + d], pv[e]);
    }
  }
  #pragma unroll
  for (int e = 0; e < NE; ++e) {
    #pragma unroll
    for (int off = 32; off; off >>= 1) {
      pg[e] += __shfl_xor(pg[e], off);
      pv[e] += __shfl_xor(pv[e], off);
    }
  }
  if (lane == 0) {
    float noisy[NE];
    #pragma unroll
    for (int e = 0; e < NE; ++e) {
      const float lg = pg[e] + gate_b[e];
      const float sd = softplus_f(pv[e] + var_b[e]);
      noisy[e] = lg + noise[t * NE + e] * sd;
    }
    int i1 = 0; float n1 = noisy[0];
    #pragma unroll
    for (int e = 1; e < NE; ++e) if (noisy[e] > n1) { n1 = noisy[e]; i1 = e; }
    int i2 = -1; float n2 = -3.0e38f;
    #pragma unroll
    for (int e = 0; e < NE; ++e) if (e != i1 && noisy[e] > n2) { n2 = noisy[e]; i2 = e; }
    const float e2 = expf(n2 - n1);
    const float den = 1.f + e2;
    coef2[t * 2 + 0] = 1.f / den;
    coef2[t * 2 + 1] = e2 / den;
    t2e[t * 2 + 0] = i1;
    t2e[t * 2 + 1] = i2;
    atomicAdd(&counts[i1], 1);
    atomicAdd(&counts[i2], 1);
  }
}

// ---------------- K2: padded segment offsets (pad to BM=256) ----------------
__global__ void moe_offsets_kernel(const int* __restrict__ counts, int* __restrict__ po) {
  if (threadIdx.x == 0) {
    int acc = 0;
    po[0] = 0;
    for (int e = 0; e < NE; ++e) {
      acc += ((counts[e] + BM - 1) / BM) * BM;
      po[e + 1] = acc;
    }
  }
}

// ---------------- K3: scatter tokens into padded slots ----------------
__global__ __launch_bounds__(256) void moe_scatter_kernel(
    const int* __restrict__ t2e, const float* __restrict__ coef2,
    const int* __restrict__ po, int* __restrict__ cnt2,
    int* __restrict__ assign_tok, float* __restrict__ slot_coef)
{
  const int t = blockIdx.x * 256 + threadIdx.x;
  if (t >= NTOK) return;
  #pragma unroll
  for (int k = 0; k < 2; ++k) {
    const int e = t2e[t * 2 + k];
    const int pos = atomicAdd(&cnt2[e], 1);
    const int slot = po[e] + pos;
    assign_tok[slot] = t;
    slot_coef[slot] = coef2[t * 2 + k];
  }
}

// ---------------- K4: f32 -> bf16 converter (grid-stride over float4) ----------------
__global__ __launch_bounds__(256) void cvt_bf16_kernel(const float* __restrict__ src,
                                                       bf16* __restrict__ dst, int n4) {
  for (int i = blockIdx.x * 256 + threadIdx.x; i < n4; i += gridDim.x * 256) {
    const float4 f = ((const float4*)src)[i];
    bf16x4 v;
    v[0] = (bf16)f.x; v[1] = (bf16)f.y; v[2] = (bf16)f.z; v[3] = (bf16)f.w;
    ((bf16x4*)dst)[i] = v;
  }
}

// ---------------- K5/K6: grouped GEMM, 256^2 tile, 8 waves, 2-phase dbuf ----------------
// A rows: ffn1 -> gathered token rows of xb; ffn2 -> contiguous h rows.
// B rows: expert weight rows (row stride == KDIM for both layers).
// LDS: both-sides XOR swizzle (chunk c8 at row r holds source chunk c8^(r&7)).
template<int KDIM, int NCOLS, bool FFN1>
__global__ __launch_bounds__(512, 2) void moe_gemm_kernel(
    const bf16* __restrict__ Asrc, const bf16* __restrict__ Wsrc,
    const float* __restrict__ bias,
    const int* __restrict__ assign_tok, const float* __restrict__ slot_coef,
    const int* __restrict__ po,
    bf16* __restrict__ hout, float* __restrict__ out,
    int chunk_base, int gx)
{
  __shared__ bf16 smA[2][BM * BK];
  __shared__ bf16 smB[2][BN * BK];
  __shared__ int toks[BM];

  // bijective XCD chunk swizzle (m204): each XCD owns a contiguous wg range
  const int nwg = gx * (NCOLS / BN);
  const int lin = blockIdx.x;
  const int q = nwg >> 3, r = nwg & 7;
  const int xcd = lin & 7, idx = lin >> 3;
  const int wg = (xcd < r ? xcd * (q + 1) : r * (q + 1) + (xcd - r) * q) + idx;
  const int bx = wg % gx, by = wg / gx;

  const int row0 = chunk_base + bx * BM;
  const int po8 = po[NE];
  if (row0 >= po8) return;
  int e = 0;
  while (row0 >= po[e + 1]) ++e;
  const int bn0 = by * BN;
  const bf16* We = Wsrc + (size_t)e * ((size_t)HH * DD);

  const int tid = threadIdx.x, lane = tid & 63;
  if (tid < BM) toks[tid] = assign_tok[row0 + tid];
  __syncthreads();

  // staging pointers: thread t, chunk i -> row = (i*512+t)>>3, src chunk (t&7)^(row&7)
  const int t7 = tid & 7;
  const bf16* aptr[4];
  const bf16* bptr[4];
  #pragma unroll
  for (int i = 0; i < 4; ++i) {
    const int g = i * 512 + tid;
    const int row = g >> 3;
    const int c8 = ((t7 ^ (row & 7)) * 8);
    int ar;
    if constexpr (FFN1) {
      const int s = toks[row];
      ar = s < 0 ? 0 : s;
    } else {
      ar = row0 - chunk_base + row;
    }
    aptr[i] = Asrc + (size_t)ar * KDIM + c8;
    bptr[i] = We + (size_t)(bn0 + row) * KDIM + c8;
  }

  auto stage = [&](int sel, int k0) {
    #pragma unroll
    for (int i = 0; i < 4; ++i)
      gload16(aptr[i] + k0, &smA[sel][(i * 512 + tid) * 8]);
    #pragma unroll
    for (int i = 0; i < 4; ++i)
      gload16(bptr[i] + k0, &smB[sel][(i * 512 + tid) * 8]);
  };

  const int wid = tid >> 6, wr = wid >> 2, wc = wid & 3;  // 2x4 wave grid
  const int la = lane & 15, hi = lane >> 4;
  f32x4 acc[8][4];
  #pragma unroll
  for (int m = 0; m < 8; ++m)
    #pragma unroll
    for (int n = 0; n < 4; ++n) acc[m][n] = {0.f, 0.f, 0.f, 0.f};

  constexpr int NK = KDIM / BK;
  stage(0, 0);
  __syncthreads();                       // prologue drain (vmcnt 0)
  #pragma unroll 2
  for (int ks = 0; ks < NK; ++ks) {
    const int cur = ks & 1;
    if (ks + 1 < NK) stage(cur ^ 1, (ks + 1) * BK);   // prefetch next tile
    const bf16* A = smA[cur];
    const bf16* B = smB[cur];
    #pragma unroll
    for (int kk = 0; kk < 2; ++kk) {
      bf16x8 af[8], bf_[4];
      #pragma unroll
      for (int m = 0; m < 8; ++m) {
        const int rw = wr * 128 + m * 16 + la;
        const int c8 = ((kk * 4 + hi) ^ (rw & 7)) * 8;
        af[m] = *(const bf16x8*)(A + rw * 64 + c8);
      }
      #pragma unroll
      for (int n = 0; n < 4; ++n) {
        const int rw = wc * 64 + n * 16 + la;
        const int c8 = ((kk * 4 + hi) ^ (rw & 7)) * 8;
        bf_[n] = *(const bf16x8*)(B + rw * 64 + c8);
      }
      #pragma unroll
      for (int m = 0; m < 8; ++m)
        #pragma unroll
        for (int n = 0; n < 4; ++n)
          acc[m][n] = __builtin_amdgcn_mfma_f32_16x16x32_bf16(af[m], bf_[n], acc[m][n], 0, 0, 0);
    }
    __syncthreads();   // drains vmcnt(0) for the prefetch + protects dbuf swap
  }

  if constexpr (FFN1) {
    #pragma unroll
    for (int n = 0; n < 4; ++n) {
      const int col = bn0 + wc * 64 + n * 16 + la;
      const float bb = bias[e * NCOLS + col];
      #pragma unroll
      for (int m = 0; m < 8; ++m) {
        const int rl = wr * 128 + m * 16 + hi * 4;
        #pragma unroll
        for (int rr = 0; rr < 4; ++rr) {
          float v = acc[m][n][rr] + bb;
          v = v > 0.f ? v : 0.f;
          hout[(size_t)(row0 - chunk_base + rl + rr) * HH + col] = (bf16)v;
        }
      }
    }
  } else {
    #pragma unroll
    for (int n = 0; n < 4; ++n) {
      const int col = bn0 + wc * 64 + n * 16 + la;
      const float bb = bias[e * NCOLS + col];
      #pragma unroll
      for (int m = 0; m < 8; ++m) {
        const int rl = wr * 128 + m * 16 + hi * 4;
        #pragma unroll
        for (int rr = 0; rr < 4; ++rr) {
          const int tl = rl + rr;
          const int tok = toks[tl];
          if (tok >= 0) {
            const float c = slot_coef[row0 + tl];
            atomicAdd(out + (size_t)tok * DD + col, c * (acc[m][n][rr] + bb));
          }
        }
      }
    }
  }
}

extern "C" void kernel_launch(void* const* d_in, const int* in_sizes, int n_in,
                              void* d_out, int out_size, void* d_ws, size_t ws_size,
                              hipStream_t stream) {
  const float* x      = (const float*)d_in[0];
  const float* noise  = (const float*)d_in[1];
  const float* gate_w = (const float*)d_in[2];
  const float* gate_b = (const float*)d_in[3];
  const float* var_w  = (const float*)d_in[4];
  const float* var_b  = (const float*)d_in[5];
  const float* w1     = (const float*)d_in[6];
  const float* b1     = (const float*)d_in[7];
  const float* w2     = (const float*)d_in[8];
  const float* b2     = (const float*)d_in[9];
  float* out = (float*)d_out;
  (void)in_sizes; (void)n_in; (void)out_size;

  char* ws = (char*)d_ws;
  size_t off = 0;
  auto alloc = [&](size_t bytes) {
    off = (off + 255) & ~(size_t)255;
    size_t o = off;
    off += bytes;
    return o;
  };
  bf16*  xb         = (bf16*)(ws + alloc((size_t)NTOK * DD * 2));
  float* coef2      = (float*)(ws + alloc((size_t)NTOK * 2 * 4));
  int*   t2e        = (int*)(ws + alloc((size_t)NTOK * 2 * 4));
  int*   counts     = (int*)(ws + alloc(64));   // counts[8] + cnt2[8]
  int*   cnt2       = counts + 8;
  int*   po         = (int*)(ws + alloc(64));
  int*   assign_tok = (int*)(ws + alloc((size_t)SLOT_CAP * 4));
  float* slot_coef  = (float*)(ws + alloc((size_t)SLOT_CAP * 4));
  bf16*  w1b        = (bf16*)(ws + alloc((size_t)NE * HH * DD * 2));  // 64 MB
  bf16*  w2b        = (bf16*)(ws + alloc((size_t)NE * DD * HH * 2));  // 64 MB
  off = (off + 255) & ~(size_t)255;
  const size_t h_avail = ws_size > off ? ws_size - off : 0;
  int chunk_rows = (int)(h_avail / ((size_t)HH * 2));
  chunk_rows = (chunk_rows / BM) * BM;
  if (chunk_rows < BM) chunk_rows = BM;
  if (chunk_rows > SLOT_CAP) chunk_rows = SLOT_CAP;
  bf16* hbuf = (bf16*)(ws + off);

  hipMemsetAsync(counts, 0, 64, stream);
  hipMemsetAsync(assign_tok, 0xFF, (size_t)SLOT_CAP * 4, stream);  // -1
  hipMemsetAsync(out, 0, (size_t)NTOK * DD * 4, stream);

  moe_gate_kernel<<<NTOK, 64, 0, stream>>>(x, noise, gate_w, gate_b, var_w, var_b,
                                           coef2, t2e, counts);
  moe_offsets_kernel<<<1, 64, 0, stream>>>(counts, po);
  moe_scatter_kernel<<<NTOK / 256, 256, 0, stream>>>(t2e, coef2, po, cnt2,
                                                     assign_tok, slot_coef);
  cvt_bf16_kernel<<<2048, 256, 0, stream>>>(x, xb, NTOK * DD / 4);
  cvt_bf16_kernel<<<2048, 256, 0, stream>>>(w1, w1b, NE * HH * DD / 4);
  cvt_bf16_kernel<<<2048, 256, 0, stream>>>(w2, w2b, NE * DD * HH / 4);

  const int rounds = (SLOT_CAP + chunk_rows - 1) / chunk_rows;
  for (int r = 0; r < rounds; ++r) {
    const int cb = r * chunk_rows;
    const int rows_here = (cb + chunk_rows <= SLOT_CAP) ? chunk_rows : (SLOT_CAP - cb);
    const int gx = rows_here / BM;
    moe_gemm_kernel<DD, HH, true><<<gx * (HH / BN), 512, 0, stream>>>(
        xb, w1b, b1, assign_tok, slot_coef, po, hbuf, nullptr, cb, gx);
    moe_gemm_kernel<HH, DD, false><<<gx * (DD / BN), 512, 0, stream>>>(
        hbuf, w2b, b2, assign_tok, slot_coef, po, nullptr, out, cb, gx);
  }
}

// Round 4
// 952.538 us; speedup vs baseline: 1.0446x; 1.0446x over previous
//
#include <hip/hip_runtime.h>
#include <hip/hip_bf16.h>
#include <math.h>

#define NTOK 8192     // B*T
#define DD   1024
#define HH   4096
#define NE   8
#define BM 256
#define BN 256
#define SLOT_CAP (2 * NTOK + NE * BM)   // 18432

typedef __bf16 bf16;
typedef __bf16 bf16x8 __attribute__((ext_vector_type(8)));
typedef __bf16 bf16x4 __attribute__((ext_vector_type(4)));
typedef float  f32x4  __attribute__((ext_vector_type(4)));

typedef __attribute__((address_space(3))) unsigned char lds_u8;
typedef const __attribute__((address_space(1))) unsigned char g_u8;

__device__ __forceinline__ void gload16(const bf16* g, bf16* l) {
  __builtin_amdgcn_global_load_lds((g_u8*)g, (lds_u8*)l, 16, 0, 0);
}

__device__ __forceinline__ float softplus_f(float v) {
  return fmaxf(v, 0.f) + log1pf(expf(-fabsf(v)));
}

// ---------------- K1: gating (1 wave per token) ----------------
__global__ __launch_bounds__(64) void moe_gate_kernel(
    const float* __restrict__ x, const float* __restrict__ noise,
    const float* __restrict__ gate_w, const float* __restrict__ gate_b,
    const float* __restrict__ var_w,  const float* __restrict__ var_b,
    float* __restrict__ coef2, int* __restrict__ t2e, int* __restrict__ counts)
{
  const int t = blockIdx.x;
  const int lane = threadIdx.x;
  const float* xt = x + (size_t)t * DD;
  float pg[NE], pv[NE];
  #pragma unroll
  for (int e = 0; e < NE; ++e) { pg[e] = 0.f; pv[e] = 0.f; }
  #pragma unroll 4
  for (int i = 0; i < DD / 64; ++i) {
    const int d = lane + i * 64;
    const float xv = xt[d];
    #pragma unroll
    for (int e = 0; e < NE; ++e) {
      pg[e] = fmaf(xv, gate_w[e * DD + d], pg[e]);
      pv[e] = fmaf(xv, var_w[e * DD + d], pv[e]);
    }
  }
  #pragma unroll
  for (int e = 0; e < NE; ++e) {
    #pragma unroll
    for (int off = 32; off; off >>= 1) {
      pg[e] += __shfl_xor(pg[e], off);
      pv[e] += __shfl_xor(pv[e], off);
    }
  }
  if (lane == 0) {
    float noisy[NE];
    #pragma unroll
    for (int e = 0; e < NE; ++e) {
      const float lg = pg[e] + gate_b[e];
      const float sd = softplus_f(pv[e] + var_b[e]);
      noisy[e] = lg + noise[t * NE + e] * sd;
    }
    int i1 = 0; float n1 = noisy[0];
    #pragma unroll
    for (int e = 1; e < NE; ++e) if (noisy[e] > n1) { n1 = noisy[e]; i1 = e; }
    int i2 = -1; float n2 = -3.0e38f;
    #pragma unroll
    for (int e = 0; e < NE; ++e) if (e != i1 && noisy[e] > n2) { n2 = noisy[e]; i2 = e; }
    const float e2 = expf(n2 - n1);
    const float den = 1.f + e2;
    coef2[t * 2 + 0] = 1.f / den;
    coef2[t * 2 + 1] = e2 / den;
    t2e[t * 2 + 0] = i1;
    t2e[t * 2 + 1] = i2;
    atomicAdd(&counts[i1], 1);
    atomicAdd(&counts[i2], 1);
  }
}

// ---------------- K2: padded segment offsets (pad to BM=256) ----------------
__global__ void moe_offsets_kernel(const int* __restrict__ counts, int* __restrict__ po) {
  if (threadIdx.x == 0) {
    int acc = 0;
    po[0] = 0;
    for (int e = 0; e < NE; ++e) {
      acc += ((counts[e] + BM - 1) / BM) * BM;
      po[e + 1] = acc;
    }
  }
}

// ---------------- K3: scatter tokens into padded slots ----------------
__global__ __launch_bounds__(256) void moe_scatter_kernel(
    const int* __restrict__ t2e, const float* __restrict__ coef2,
    const int* __restrict__ po, int* __restrict__ cnt2,
    int* __restrict__ assign_tok, float* __restrict__ slot_coef)
{
  const int t = blockIdx.x * 256 + threadIdx.x;
  if (t >= NTOK) return;
  #pragma unroll
  for (int k = 0; k < 2; ++k) {
    const int e = t2e[t * 2 + k];
    const int pos = atomicAdd(&cnt2[e], 1);
    const int slot = po[e] + pos;
    assign_tok[slot] = t;
    slot_coef[slot] = coef2[t * 2 + k];
  }
}

// ---------------- K4: f32 -> bf16 converter (grid-stride over float4) ----------------
__global__ __launch_bounds__(256) void cvt_bf16_kernel(const float* __restrict__ src,
                                                       bf16* __restrict__ dst, int n4) {
  for (int i = blockIdx.x * 256 + threadIdx.x; i < n4; i += gridDim.x * 256) {
    const float4 f = ((const float4*)src)[i];
    bf16x4 v;
    v[0] = (bf16)f.x; v[1] = (bf16)f.y; v[2] = (bf16)f.z; v[3] = (bf16)f.w;
    ((bf16x4*)dst)[i] = v;
  }
}

// ---------------- grouped GEMM: 256^2 tile, 8 waves, counted-vmcnt phase ring ----------------
// LDS per operand = ring of 4 half-K regions (256 rows x 32 cols bf16, 16 KB each).
// Pair pp of iter i: reads region pp (k-half 4i+pp), stages k-half 4i+3+pp into
// region (pp+3)&3 (freed in pair pp-1). Steady state: 12 loads in flight at each
// wait; vmcnt(8) lands exactly the region about to be read. No vmcnt(0) in loop.
// Swizzle: phys chunk16 = logical chunk ^ (row&3) on both stage-source and ds_read.
template<int KDIM, int KSTRIDE, int NCOLS, bool FFN1>
__global__ __launch_bounds__(512, 2) void moe_gemm8_kernel(
    const bf16* __restrict__ Asrc, const bf16* __restrict__ Wsrc,
    const float* __restrict__ bias,
    const int* __restrict__ assign_tok, const float* __restrict__ slot_coef,
    const int* __restrict__ po,
    bf16* __restrict__ hout, float* __restrict__ out,
    int chunk_base, int gx)
{
  constexpr int NI  = KDIM / 128;   // 4 k-halves per iter
  constexpr int KHT = KDIM / 32;    // total k-halves (power of 2)
  __shared__ bf16 smA[32768];       // 4 regions x 8192 elems = 64 KB
  __shared__ bf16 smB[32768];
  __shared__ int toks[BM];

  // bijective XCD chunk swizzle (m204)
  const int nwg = gx * (NCOLS / BN);
  const int lin = blockIdx.x;
  const int q = nwg >> 3, r = nwg & 7;
  const int xcd = lin & 7, idx = lin >> 3;
  const int wg = (xcd < r ? xcd * (q + 1) : r * (q + 1) + (xcd - r) * q) + idx;
  const int bx = wg % gx, by = wg / gx;

  const int row0 = chunk_base + bx * BM;
  const int po8 = po[NE];
  if (row0 >= po8) return;
  int e = 0;
  while (row0 >= po[e + 1]) ++e;
  const int bn0 = by * BN;
  const size_t kbase = (size_t)blockIdx.z * KDIM;     // K-split offset (ffn2)
  const bf16* We = Wsrc + (size_t)e * ((size_t)HH * DD) + kbase;
  const bf16* As = Asrc + kbase;

  const int tid = threadIdx.x, lane = tid & 63, wid = tid >> 6;
  if (tid < BM) toks[tid] = assign_tok[row0 + tid];
  __syncthreads();

  // ---- staging source pointers (per-lane, pre-swizzled source chunk) ----
  // stage instr j (j=0,1) of wave wid covers tile rows (j*8+wid)*16 .. +15;
  // lane l -> row offset l>>2, phys chunk l&3, so source logical chunk =
  // (l&3) ^ ((l>>2)&3)  (row&3 == (l>>2)&3 since base row is a multiple of 16).
  const int srcc = (((lane & 3) ^ ((lane >> 2) & 3)) * 8);
  const int rt0 = wid * 16 + (lane >> 2);
  const int rt1 = (8 + wid) * 16 + (lane >> 2);
  int ar0, ar1;
  if constexpr (FFN1) {
    const int s0 = toks[rt0]; ar0 = s0 < 0 ? 0 : s0;
    const int s1 = toks[rt1]; ar1 = s1 < 0 ? 0 : s1;
  } else {
    ar0 = row0 - chunk_base + rt0;
    ar1 = row0 - chunk_base + rt1;
  }
  const bf16* ap0 = As + (size_t)ar0 * KSTRIDE + srcc;
  const bf16* ap1 = As + (size_t)ar1 * KSTRIDE + srcc;
  const bf16* bp0 = We + (size_t)(bn0 + rt0) * KSTRIDE + srcc;
  const bf16* bp1 = We + (size_t)(bn0 + rt1) * KSTRIDE + srcc;

  auto stage = [&](int rr, int kh) {
    const int ko = kh * 32;
    gload16(ap0 + ko, &smA[rr * 8192 + wid * 512]);
    gload16(ap1 + ko, &smA[rr * 8192 + (8 + wid) * 512]);
    gload16(bp0 + ko, &smB[rr * 8192 + wid * 512]);
    gload16(bp1 + ko, &smB[rr * 8192 + (8 + wid) * 512]);
  };

  // ---- fragment read bases ----
  const int wr = wid >> 2, wc = wid & 3;        // 2(M) x 4(N) wave grid
  const int la = lane & 15, hi = lane >> 4;
  const int cph = (hi ^ (la & 3)) * 8;          // phys chunk for logical chunk hi
  const int aBase = wr * 4096 + la * 32 + cph;  // + m*512 per 16-row frag
  const int bBase = wc * 2048 + la * 32 + cph;  // + n*512

  f32x4 acc[8][4];
  #pragma unroll
  for (int m = 0; m < 8; ++m)
    #pragma unroll
    for (int n = 0; n < 4; ++n) acc[m][n] = {0.f, 0.f, 0.f, 0.f};

  // prologue: prime 3 stage events (12 loads in flight at first wait)
  stage(0, 0); stage(1, 1); stage(2, 2);

  for (int i = 0; i < NI; ++i) {
    #pragma unroll
    for (int pp = 0; pp < 4; ++pp) {
      asm volatile("s_waitcnt vmcnt(8)" ::: "memory");
      asm volatile("s_barrier" ::: "memory");
      bf16x8 a0[4], bb[4];
      #pragma unroll
      for (int m = 0; m < 4; ++m)
        a0[m] = *(const bf16x8*)(&smA[pp * 8192 + aBase + m * 512]);
      #pragma unroll
      for (int n = 0; n < 4; ++n)
        bb[n] = *(const bf16x8*)(&smB[pp * 8192 + bBase + n * 512]);
      stage((pp + 3) & 3, (i * 4 + 3 + pp) & (KHT - 1));
      __builtin_amdgcn_s_setprio(1);
      #pragma unroll
      for (int m = 0; m < 4; ++m)
        #pragma unroll
        for (int n = 0; n < 4; ++n)
          acc[m][n] = __builtin_amdgcn_mfma_f32_16x16x32_bf16(a0[m], bb[n], acc[m][n], 0, 0, 0);
      __builtin_amdgcn_s_setprio(0);
      bf16x8 a1[4];
      #pragma unroll
      for (int m = 0; m < 4; ++m)
        a1[m] = *(const bf16x8*)(&smA[pp * 8192 + aBase + (4 + m) * 512]);
      __builtin_amdgcn_s_setprio(1);
      #pragma unroll
      for (int m = 0; m < 4; ++m)
        #pragma unroll
        for (int n = 0; n < 4; ++n)
          acc[4 + m][n] = __builtin_amdgcn_mfma_f32_16x16x32_bf16(a1[m], bb[n], acc[4 + m][n], 0, 0, 0);
      __builtin_amdgcn_s_setprio(0);
    }
  }

  if constexpr (FFN1) {
    const int hrow0 = row0 - chunk_base;
    #pragma unroll
    for (int n = 0; n < 4; ++n) {
      const int col = bn0 + wc * 64 + n * 16 + la;
      const float bb = bias[e * NCOLS + col];
      #pragma unroll
      for (int m = 0; m < 8; ++m) {
        const int rl = wr * 128 + m * 16 + hi * 4;
        #pragma unroll
        for (int rr = 0; rr < 4; ++rr) {
          float v = acc[m][n][rr] + bb;
          v = v > 0.f ? v : 0.f;
          hout[(size_t)(hrow0 + rl + rr) * HH + col] = (bf16)v;
        }
      }
    }
  } else {
    const bool addb = (blockIdx.z == 0);
    #pragma unroll
    for (int n = 0; n < 4; ++n) {
      const int col = bn0 + wc * 64 + n * 16 + la;
      const float bb = addb ? bias[e * NCOLS + col] : 0.f;
      #pragma unroll
      for (int m = 0; m < 8; ++m) {
        const int rl = wr * 128 + m * 16 + hi * 4;
        #pragma unroll
        for (int rr = 0; rr < 4; ++rr) {
          const int tl = rl + rr;
          const int tok = toks[tl];
          if (tok >= 0) {
            const float c = slot_coef[row0 + tl];
            atomicAdd(out + (size_t)tok * DD + col, c * (acc[m][n][rr] + bb));
          }
        }
      }
    }
  }
}

extern "C" void kernel_launch(void* const* d_in, const int* in_sizes, int n_in,
                              void* d_out, int out_size, void* d_ws, size_t ws_size,
                              hipStream_t stream) {
  const float* x      = (const float*)d_in[0];
  const float* noise  = (const float*)d_in[1];
  const float* gate_w = (const float*)d_in[2];
  const float* gate_b = (const float*)d_in[3];
  const float* var_w  = (const float*)d_in[4];
  const float* var_b  = (const float*)d_in[5];
  const float* w1     = (const float*)d_in[6];
  const float* b1     = (const float*)d_in[7];
  const float* w2     = (const float*)d_in[8];
  const float* b2     = (const float*)d_in[9];
  float* out = (float*)d_out;
  (void)in_sizes; (void)n_in; (void)out_size;

  char* ws = (char*)d_ws;
  size_t off = 0;
  auto alloc = [&](size_t bytes) {
    off = (off + 255) & ~(size_t)255;
    size_t o = off;
    off += bytes;
    return o;
  };
  bf16*  xb         = (bf16*)(ws + alloc((size_t)NTOK * DD * 2));
  float* coef2      = (float*)(ws + alloc((size_t)NTOK * 2 * 4));
  int*   t2e        = (int*)(ws + alloc((size_t)NTOK * 2 * 4));
  int*   counts     = (int*)(ws + alloc(64));   // counts[8] + cnt2[8]
  int*   cnt2       = counts + 8;
  int*   po         = (int*)(ws + alloc(64));
  int*   assign_tok = (int*)(ws + alloc((size_t)SLOT_CAP * 4));
  float* slot_coef  = (float*)(ws + alloc((size_t)SLOT_CAP * 4));
  bf16*  w1b        = (bf16*)(ws + alloc((size_t)NE * HH * DD * 2));  // 64 MB
  bf16*  w2b        = (bf16*)(ws + alloc((size_t)NE * DD * HH * 2));  // 64 MB
  off = (off + 255) & ~(size_t)255;
  const size_t h_avail = ws_size > off ? ws_size - off : 0;
  int chunk_rows = (int)(h_avail / ((size_t)HH * 2));
  chunk_rows = (chunk_rows / BM) * BM;
  if (chunk_rows < BM) chunk_rows = BM;
  if (chunk_rows > SLOT_CAP) chunk_rows = SLOT_CAP;
  bf16* hbuf = (bf16*)(ws + off);

  hipMemsetAsync(counts, 0, 64, stream);
  hipMemsetAsync(assign_tok, 0xFF, (size_t)SLOT_CAP * 4, stream);  // -1
  hipMemsetAsync(out, 0, (size_t)NTOK * DD * 4, stream);

  moe_gate_kernel<<<NTOK, 64, 0, stream>>>(x, noise, gate_w, gate_b, var_w, var_b,
                                           coef2, t2e, counts);
  moe_offsets_kernel<<<1, 64, 0, stream>>>(counts, po);
  moe_scatter_kernel<<<NTOK / 256, 256, 0, stream>>>(t2e, coef2, po, cnt2,
                                                     assign_tok, slot_coef);
  cvt_bf16_kernel<<<2048, 256, 0, stream>>>(x, xb, NTOK * DD / 4);
  cvt_bf16_kernel<<<2048, 256, 0, stream>>>(w1, w1b, NE * HH * DD / 4);
  cvt_bf16_kernel<<<2048, 256, 0, stream>>>(w2, w2b, NE * DD * HH / 4);

  const int rounds = (SLOT_CAP + chunk_rows - 1) / chunk_rows;
  for (int r = 0; r < rounds; ++r) {
    const int cb = r * chunk_rows;
    const int rows_here = (cb + chunk_rows <= SLOT_CAP) ? chunk_rows : (SLOT_CAP - cb);
    const int gx = rows_here / BM;
    dim3 g1(gx * (HH / BN), 1, 1);
    moe_gemm8_kernel<DD, DD, HH, true><<<g1, 512, 0, stream>>>(
        xb, w1b, b1, assign_tok, slot_coef, po, hbuf, nullptr, cb, gx);
    dim3 g2(gx * (DD / BN), 1, 2);   // K split in 2 halves of 2048
    moe_gemm8_kernel<HH / 2, HH, DD, false><<<g2, 512, 0, stream>>>(
        hbuf, w2b, b2, assign_tok, slot_coef, po, nullptr, out, cb, gx);
  }
}